// Round 14
// baseline (101.336 us; speedup 1.0000x reference)
//
#include <hip/hip_runtime.h>
#include <hip/hip_fp16.h>

#define BN 4
#define CN 256
#define PN 4096
#define QT 32
#define TSTR 264

typedef __attribute__((ext_vector_type(8))) short short8;
typedef __attribute__((ext_vector_type(8))) unsigned short ushort8;
typedef __attribute__((ext_vector_type(4))) unsigned short us4;
typedef __attribute__((ext_vector_type(4))) float f32x4;
typedef __attribute__((ext_vector_type(16))) float f32x16;
typedef __attribute__((ext_vector_type(4))) unsigned int u32x4;
typedef unsigned int u32;

__device__ __forceinline__ unsigned short f2bf(float f) {
  u32 u = __builtin_bit_cast(u32, f);
  return (unsigned short)((u + 0x7fffu + ((u >> 16) & 1u)) >> 16);
}

__device__ __forceinline__ void async_copy16(const void* g, void* l) {
  __builtin_amdgcn_global_load_lds((const __attribute__((address_space(1))) u32*)g,
                                   (__attribute__((address_space(3))) u32*)l, 16, 0, 0);
}

// 32-row frag-major layout (per 32-q block = 16 KB = 16 frags of 1024B):
//   xnK: frag kc, byte = blk32*16384 + kc*1024 + l*16 + j*2
//        <-> xn[q = blk32*32 + (l&31)][ch = kc*16 + (l>>5)*8 + j]
//   (serves BOTH the QKT A-operand (K) and B-operand (Q) — same k-map both sides,
//    so QKT is correct under any common hardware k-permutation.)
// gxF: per 32-q block 16 frags: frag (cb*2+chunk), elem (lane l, j):
//        V[q = qb*32 + 16*chunk + (j&3)+8*((j>>2)&1)+4*(l>>5)][c = cb*32 + (l&31)]
//   — matches the 32x32 D-layout row order of the packed S regs (cvt_pk sequential),
//     so PV contracts q-for-q by construction.

// ---- fused k_nxgx: norms + xnK + gxF
__global__ __launch_bounds__(256) void k_nxgx(const float* __restrict__ x,
                                              const float* __restrict__ Wm,
                                              const float* __restrict__ bias,
                                              unsigned short* __restrict__ xnK,
                                              unsigned short* __restrict__ gxF) {
  __shared__ unsigned short tl[64 * TSTR];
  __shared__ float red[4][64];
  __shared__ float mnl[64];
  const int b = blockIdx.y, qb = blockIdx.x;
  const int tid = threadIdx.x;
  const int tp = tid & 63, cg = tid >> 6;

  {
    const float* xp = x + ((size_t)b * CN + cg * 64) * PN + qb * 64 + tp;
    float v[64];
    float ss = 0.f;
#pragma unroll
    for (int i = 0; i < 64; ++i) {
      v[i] = xp[(size_t)i * PN];
      ss += v[i] * v[i];
    }
    red[cg][tp] = ss;
    __syncthreads();
    float nrm = sqrtf(red[0][tp] + red[1][tp] + red[2][tp] + red[3][tp]);
    float mn = fmaxf(nrm, 1e-8f);
    float rn = 1.f / mn;
    if (cg == 0) mnl[tp] = mn;
    unsigned int* tl32 = (unsigned int*)tl;
#pragma unroll
    for (int j = 0; j < 32; ++j) {
      unsigned int w = (unsigned int)f2bf(v[2 * j] * rn) |
                       ((unsigned int)f2bf(v[2 * j + 1] * rn) << 16);
      tl32[tp * (TSTR / 2) + cg * 32 + j] = w;
    }
    __syncthreads();
    // frag-major store: chunk idx = blk*1024 + kc*64 + l; byte = idx*16
    char* dstb = (char*)xnK + (size_t)b * (PN * CN * 2) + (size_t)qb * 32768;
#pragma unroll
    for (int m = 0; m < 8; ++m) {
      int idx = m * 256 + tid;
      int blk = idx >> 10, kc = (idx >> 6) & 15, l = idx & 63;
      ushort8 o = *(const ushort8*)(tl + (blk * 32 + (l & 31)) * TSTR + kc * 16 + (l >> 5) * 8);
      *(ushort8*)(dstb + (size_t)idx * 16) = o;
    }
  }

  const int wave = tid >> 6, lane = tid & 63;
  const int lr = lane & 15, g = lane >> 4;
  char* vbb = (char*)gxF + (size_t)b * (PN * CN * 2) + (size_t)qb * 32768;
  // per-lane V-perm constants (qq = lr): k = (qq&3)|(((qq>>3)&1)<<2)|(((qq>>2)&1)<<3)
  const int lh = (lr >> 2) & 1;                              // k>>3
  const int jj = (lr & 3) | (((lr >> 3) & 1) << 2);          // k&7
#pragma unroll
  for (int mp = 0; mp < 2; ++mp) {
    short8 af[2][8];
#pragma unroll
    for (int mt = 0; mt < 2; ++mt) {
      const float* wr = Wm + (size_t)(wave * 64 + mp * 32 + mt * 16 + lr) * CN;
#pragma unroll
      for (int k = 0; k < 8; ++k) {
        const float* ap = wr + k * 32 + g * 8;
        short8 a;
#pragma unroll
        for (int j = 0; j < 8; ++j) a[j] = (short)f2bf(ap[j]);
        af[mt][k] = a;
      }
    }
    f32x4 acc[2][4];
#pragma unroll
    for (int mt = 0; mt < 2; ++mt)
#pragma unroll
      for (int n = 0; n < 4; ++n) acc[mt][n] = (f32x4){0.f, 0.f, 0.f, 0.f};
#pragma unroll
    for (int n = 0; n < 4; ++n)
#pragma unroll
      for (int k = 0; k < 8; ++k) {
        short8 bf = *(const short8*)((const char*)tl + (n * 16 + lr) * (TSTR * 2) + k * 64 + g * 16);
        acc[0][n] = __builtin_amdgcn_mfma_f32_16x16x32_bf16(af[0][k], bf, acc[0][n], 0, 0, 0);
        acc[1][n] = __builtin_amdgcn_mfma_f32_16x16x32_bf16(af[1][k], bf, acc[1][n], 0, 0, 0);
      }
#pragma unroll
    for (int n = 0; n < 4; ++n) {
      float mn = mnl[n * 16 + lr];
      int blk = n >> 1, chunk = n & 1;
#pragma unroll
      for (int mt = 0; mt < 2; ++mt)
#pragma unroll
        for (int i = 0; i < 4; ++i) {
          int c = wave * 64 + mp * 32 + mt * 16 + g * 4 + i;
          float v = acc[mt][n][i] * mn + bias[c];
          int byteoff = blk * 16384 + ((((c >> 5) & 7) * 2 + chunk) << 10) +
                        (((lh << 5) | (c & 31)) << 4) + (jj << 1);
          *(unsigned short*)(vbb + byteoff) = f2bf(v);
        }
    }
  }
}

// ---- fused attention: 8-wave WG, wave = 32p x 256c (32x32x16 MFMA), QT=32,
// triple-buffered K/V (96KB), counted vmcnt(4) never draining mid-loop.
extern __shared__ char smem[];

__global__ __launch_bounds__(512, 2) void k_attn(const unsigned short* __restrict__ xnK,
                                                 const unsigned short* __restrict__ gxF,
                                                 __half* __restrict__ p0h, __half* __restrict__ p1h,
                                                 __half* __restrict__ p2h, __half* __restrict__ p3h,
                                                 int lq, int ntiles) {
  const int fid = blockIdx.x;
  const int b = fid & 3;
  const int qs = (fid >> 2) & ((1 << lq) - 1);
  const int pblk = fid >> (2 + lq);
  const int tid = threadIdx.x;
  const int wave = tid >> 6, lane = tid & 63;
  const int l31 = lane & 31, h = lane >> 5;
  const int qt0 = (qs * (PN >> lq)) >> 5;
  const int p0w = pblk * 256 + wave * 32;
  __half* dsth = (qs == 0) ? p0h : (qs == 1) ? p1h : (qs == 2) ? p2h : p3h;

  const char* xb = (const char*)xnK + (size_t)b * (PN * CN * 2);
  const char* vgb = (const char*)gxF + (size_t)b * (PN * CN * 2);
  const char* kq = xb + (size_t)qt0 * 16384;
  const char* vq = vgb + (size_t)qt0 * 16384;
  const int ldst = tid * 16;
  const int lane16 = lane * 16;

  auto issue = [&](int t) {
    char* buf = smem + (t % 3) * 32768;
    const char* ks = kq + (size_t)t * 16384 + ldst;
    const char* vs = vq + (size_t)t * 16384 + ldst;
    async_copy16(ks, buf + ldst);
    async_copy16(ks + 8192, buf + ldst + 8192);
    async_copy16(vs, buf + 16384 + ldst);
    async_copy16(vs + 8192, buf + 16384 + ldst + 8192);
  };

  // Q hoist first (plain global loads), drain, then start DMA pipeline.
  short8 qf[16];
  {
    const char* qpb = xb + (size_t)(pblk * 8 + wave) * 16384;
#pragma unroll
    for (int kc = 0; kc < 16; ++kc)
      qf[kc] = *(const short8*)(qpb + (kc << 10) + lane16);
  }
  asm volatile("s_waitcnt vmcnt(0)" ::: "memory");
  issue(0);
  issue(1);

  f32x16 yacc[8];
#pragma unroll
  for (int ct = 0; ct < 8; ++ct)
#pragma unroll
    for (int r = 0; r < 16; ++r) yacc[ct][r] = 0.f;

  for (int t = 0; t < ntiles; ++t) {
    const char* kb = smem + (t % 3) * 32768;
    const char* vb = kb + 16384;

    if (t + 1 < ntiles) {
      asm volatile("s_waitcnt vmcnt(4)" ::: "memory");  // tile t landed, t+1 in flight
    } else {
      asm volatile("s_waitcnt vmcnt(0)" ::: "memory");
    }
    __builtin_amdgcn_s_barrier();
    if (t + 2 < ntiles) issue(t + 2);  // slot (t+2)%3 == (t-1)%3, free after this barrier

    // QKT: S[32q x 32p] = sum_ch mfma32x32x16(K-frag, Q-frag)
    f32x16 sacc;
#pragma unroll
    for (int r = 0; r < 16; ++r) sacc[r] = 0.f;
    __builtin_amdgcn_s_setprio(1);
#pragma unroll
    for (int kc = 0; kc < 16; ++kc) {
      short8 kf = *(const short8*)(kb + (kc << 10) + lane16);
      sacc = __builtin_amdgcn_mfma_f32_32x32x16_bf16(kf, qf[kc], sacc, 0, 0, 0);
    }
    __builtin_amdgcn_s_setprio(0);

    // relu^2 -> sequential cvt_pk pack: regs 0..7 -> A-frag a, 8..15 -> A-frag b
    u32 pw[8];
#pragma unroll
    for (int w = 0; w < 8; ++w) {
      float x0 = fmaxf(sacc[2 * w], 0.f); x0 *= x0;
      float x1 = fmaxf(sacc[2 * w + 1], 0.f); x1 *= x1;
      asm("v_cvt_pk_bf16_f32 %0, %1, %2" : "=v"(pw[w]) : "v"(x0), "v"(x1));
    }
    u32x4 wa = {pw[0], pw[1], pw[2], pw[3]};
    u32x4 wb = {pw[4], pw[5], pw[6], pw[7]};
    short8 aa = __builtin_bit_cast(short8, wa);
    short8 ab = __builtin_bit_cast(short8, wb);

    // PV: Y[32p x 256c] += S^T @ V  (V pre-permuted to match packed S row order)
    __builtin_amdgcn_s_setprio(1);
#pragma unroll
    for (int ct = 0; ct < 8; ++ct) {
      short8 vfa = *(const short8*)(vb + ((ct * 2) << 10) + lane16);
      yacc[ct] = __builtin_amdgcn_mfma_f32_32x32x16_bf16(aa, vfa, yacc[ct], 0, 0, 0);
      short8 vfb = *(const short8*)(vb + ((ct * 2 + 1) << 10) + lane16);
      yacc[ct] = __builtin_amdgcn_mfma_f32_32x32x16_bf16(ab, vfb, yacc[ct], 0, 0, 0);
    }
    __builtin_amdgcn_s_setprio(0);
  }
  __builtin_amdgcn_s_barrier();

  // ---- epilogue: per-wave LDS transpose (4352B region), f16 partial stores
  // yacc[ct][r] = y[p = p0w + (r&3)+8*(r>>2)+4*h][c = ct*32 + l31]
  float* yl = (float*)(smem + wave * 4352);
#pragma unroll
  for (int ct = 0; ct < 8; ++ct) {
#pragma unroll
    for (int r = 0; r < 16; ++r)
      yl[l31 * 33 + ((r & 3) + 8 * (r >> 2) + 4 * h)] = yacc[ct][r];
#pragma unroll
    for (int i2 = 0; i2 < 4; ++i2) {
      int c_l = i2 * 8 + (lane >> 3);
      int p4 = (lane & 7) * 4;
      float4 v = *(const float4*)(yl + c_l * 33 + p4);
      size_t off = ((size_t)b * CN + ct * 32 + c_l) * PN + p0w + p4;
      us4 h4;
      h4[0] = __builtin_bit_cast(unsigned short, __float2half(v.x));
      h4[1] = __builtin_bit_cast(unsigned short, __float2half(v.y));
      h4[2] = __builtin_bit_cast(unsigned short, __float2half(v.z));
      h4[3] = __builtin_bit_cast(unsigned short, __float2half(v.w));
      *(us4*)(dsth + off) = h4;
    }
  }
}

// ---- final reduction: out = sum of np f16 partials
__global__ void k_add(float* __restrict__ o, const uint2* __restrict__ a,
                      const uint2* __restrict__ bb, const uint2* __restrict__ c,
                      const uint2* __restrict__ d, int np, int n4) {
  int i = blockIdx.x * blockDim.x + threadIdx.x;
  int stride = gridDim.x * blockDim.x;
  float4* o4 = (float4*)o;
  for (; i < n4; i += stride) {
    uint2 ua = a[i];
    float2 f0 = __half22float2(__builtin_bit_cast(__half2, ua.x));
    float2 f1 = __half22float2(__builtin_bit_cast(__half2, ua.y));
    float4 r = {f0.x, f0.y, f1.x, f1.y};
    uint2 ub = bb[i];
    f0 = __half22float2(__builtin_bit_cast(__half2, ub.x));
    f1 = __half22float2(__builtin_bit_cast(__half2, ub.y));
    r.x += f0.x; r.y += f0.y; r.z += f1.x; r.w += f1.y;
    if (np > 2) {
      uint2 uc = c[i];
      f0 = __half22float2(__builtin_bit_cast(__half2, uc.x));
      f1 = __half22float2(__builtin_bit_cast(__half2, uc.y));
      r.x += f0.x; r.y += f0.y; r.z += f1.x; r.w += f1.y;
      uint2 ud = d[i];
      f0 = __half22float2(__builtin_bit_cast(__half2, ud.x));
      f1 = __half22float2(__builtin_bit_cast(__half2, ud.y));
      r.x += f0.x; r.y += f0.y; r.z += f1.x; r.w += f1.y;
    }
    o4[i] = r;
  }
}

extern "C" void kernel_launch(void* const* d_in, const int* in_sizes, int n_in,
                              void* d_out, int out_size, void* d_ws, size_t ws_size,
                              hipStream_t stream) {
  const float* x = (const float*)d_in[0];
  const float* Wm = (const float*)d_in[1];
  const float* bias = (const float*)d_in[2];
  float* out = (float*)d_out;

  char* ws = (char*)d_ws;
  unsigned short* xnK = (unsigned short*)ws;                        // 8 MB frag-major xn
  unsigned short* gxF = (unsigned short*)(ws + (size_t)8388608);    // 8 MB frag-major permuted V
  __half* p0 = (__half*)(ws + (size_t)16777216);                    // f16 partials x4 (8 MB each)
  __half* p1 = p0 + 4194304;
  __half* p2 = p1 + 4194304;
  __half* p3 = p2 + 4194304;
  const size_t need4 = 16777216ULL + 4ULL * 8388608ULL;

  hipFuncSetAttribute(reinterpret_cast<const void*>(k_attn),
                      hipFuncAttributeMaxDynamicSharedMemorySize, 98304);

  k_nxgx<<<dim3(PN / 64, BN), 256, 0, stream>>>(x, Wm, bias, xnK, gxF);
  if (ws_size >= need4) {
    k_attn<<<dim3(256), 512, 98304, stream>>>(xnK, gxF, p0, p1, p2, p3, 2, (PN / 4) / QT);
    k_add<<<dim3(1024), 256, 0, stream>>>(out, (const uint2*)p0, (const uint2*)p1,
                                          (const uint2*)p2, (const uint2*)p3, 4, BN * CN * PN / 4);
  } else {
    k_attn<<<dim3(128), 512, 98304, stream>>>(xnK, gxF, p0, p1, p0, p1, 1, (PN / 2) / QT);
    k_add<<<dim3(1024), 256, 0, stream>>>(out, (const uint2*)p0, (const uint2*)p1,
                                          (const uint2*)p0, (const uint2*)p1, 2, BN * CN * PN / 4);
  }
}